// Round 1
// baseline (873.117 us; speedup 1.0000x reference)
//
#include <hip/hip_runtime.h>
#include <math.h>

#define NN 50000
#define EE 800000
#define FIN 128
#define FOUT 32
#define HEADS 8
#define NT 16
#define HF 256          // HEADS*FOUT
#define TH (NT*HEADS)   // 128

// ---- float<->ordered-uint mapping for atomicMax on floats ----
__device__ __forceinline__ unsigned fmap(float f) {
    unsigned u = __float_as_uint(f);
    return (u & 0x80000000u) ? ~u : (u | 0x80000000u);
}
__device__ __forceinline__ float funmap(unsigned u) {
    u = (u & 0x80000000u) ? (u & 0x7FFFFFFFu) : ~u;
    return __uint_as_float(u);
}

// ---- Kernel A: projection + a1 + node_type, NPB nodes per 256-thread block ----
#define NPB 8
__global__ __launch_bounds__(256) void k_project(
    const float* __restrict__ x, const float* __restrict__ fc_w,
    const float* __restrict__ attn_l, const float* __restrict__ attn_r,
    float* __restrict__ nf, float* __restrict__ a1, float* __restrict__ nt)
{
    __shared__ float xs[NPB][FIN];
    __shared__ float ps[NPB][HF];
    const int t = threadIdx.x;
    const int node0 = blockIdx.x * NPB;

    for (int i = t; i < NPB * FIN; i += 256) {
        int ni = i >> 7, k = i & 127;
        int n = node0 + ni;
        xs[ni][k] = (n < NN) ? x[n * FIN + k] : 0.f;
    }
    __syncthreads();

    float acc[NPB];
#pragma unroll
    for (int i = 0; i < NPB; i++) acc[i] = 0.f;
    for (int k = 0; k < FIN; k++) {
        float w = fc_w[k * HF + t];
#pragma unroll
        for (int i = 0; i < NPB; i++) acc[i] += xs[i][k] * w;
    }
#pragma unroll
    for (int i = 0; i < NPB; i++) {
        ps[i][t] = acc[i];
        int n = node0 + i;
        if (n < NN) nf[n * HF + t] = acc[i];
    }
    __syncthreads();

    // a1: NPB*HEADS = 64 tasks
    if (t < NPB * HEADS) {
        int ni = t >> 3, h = t & 7;
        float s = 0.f;
#pragma unroll
        for (int f = 0; f < FOUT; f++) s += ps[ni][f * HEADS + h] * attn_l[f * HEADS + h];
        int n = node0 + ni;
        if (n < NN) a1[n * HEADS + h] = s;
    }
    // node_type: NPB*NT*HEADS = 1024 tasks
    for (int task = t; task < NPB * TH; task += 256) {
        int ni = task / TH;
        int rem = task % TH;
        int tt = rem >> 3, h = rem & 7;
        const float* ar = attn_r + tt * (FOUT * HEADS);
        float s = 0.f;
#pragma unroll
        for (int f = 0; f < FOUT; f++) s += ps[ni][f * HEADS + h] * ar[f * HEADS + h];
        int n = node0 + ni;
        if (n < NN) nt[n * TH + rem] = s;
    }
}

// ---- Kernel B: edge logits + leaky relu + atomic segment max ----
__global__ __launch_bounds__(256) void k_logits(
    const float* __restrict__ a1, const float* __restrict__ nt,
    const int* __restrict__ src, const int* __restrict__ dst,
    const int* __restrict__ et,
    float* __restrict__ A, unsigned* __restrict__ M)
{
    int idx = blockIdx.x * 256 + threadIdx.x;
    if (idx >= EE * HEADS) return;
    int e = idx >> 3, h = idx & 7;
    int d = dst[e], s = src[e], ty = et[e];
    float a = a1[d * HEADS + h] + nt[s * TH + ty * HEADS + h];
    a = (a > 0.f) ? a : 0.2f * a;
    A[idx] = a;
    atomicMax(&M[d * HEADS + h], fmap(a));
}

// ---- Kernel C: ex = exp(a - m[dst]); atomic segment sum ----
__global__ __launch_bounds__(256) void k_expsum(
    const int* __restrict__ dst, const unsigned* __restrict__ M,
    float* __restrict__ A, float* __restrict__ den)
{
    int idx = blockIdx.x * 256 + threadIdx.x;
    if (idx >= EE * HEADS) return;
    int e = idx >> 3, h = idx & 7;
    int d = dst[e];
    float m = funmap(M[d * HEADS + h]);
    float ex = expf(A[idx] - m);
    A[idx] = ex;
    atomicAdd(&den[d * HEADS + h], ex);
}

// ---- Kernel D: attn = ex / den[dst] (in place in d_out) ----
__global__ __launch_bounds__(256) void k_norm(
    const int* __restrict__ dst, const float* __restrict__ den,
    float* __restrict__ A)
{
    int idx = blockIdx.x * 256 + threadIdx.x;
    if (idx >= EE * HEADS) return;
    int e = idx >> 3, h = idx & 7;
    A[idx] = A[idx] / den[dst[e] * HEADS + h];
}

// ---- Kernel E: message aggregation, one block per edge ----
__global__ __launch_bounds__(256) void k_agg(
    const float* __restrict__ nf, const float* __restrict__ attn,
    const int* __restrict__ src, const int* __restrict__ dst,
    float* __restrict__ hout)
{
    int e = blockIdx.x;
    int j = threadIdx.x;
    int s = src[e], d = dst[e];
    float v = nf[s * HF + j] * attn[e * HEADS + (j & 7)];
    atomicAdd(&hout[d * HF + j], v);
}

// ---- Kernel F: bias + head-mean + ELU ----
__global__ __launch_bounds__(256) void k_final(
    const float* __restrict__ hout, const float* __restrict__ bias,
    float* __restrict__ ret)
{
    int idx = blockIdx.x * 256 + threadIdx.x;
    if (idx >= NN * FOUT) return;
    int n = idx >> 5, f2 = idx & 31;
    float s = 0.f;
#pragma unroll
    for (int h2 = 0; h2 < HEADS; h2++)
        s += hout[n * HF + h2 * FOUT + f2] + bias[h2 * FOUT + f2];
    s *= 0.125f;
    ret[idx] = (s > 0.f) ? s : (expf(s) - 1.f);
}

extern "C" void kernel_launch(void* const* d_in, const int* in_sizes, int n_in,
                              void* d_out, int out_size, void* d_ws, size_t ws_size,
                              hipStream_t stream)
{
    const float* x      = (const float*)d_in[0];
    const float* fc_w   = (const float*)d_in[1];
    const float* attn_l = (const float*)d_in[2];
    const float* attn_r = (const float*)d_in[3];
    const float* bias   = (const float*)d_in[4];
    const int*   src    = (const int*)d_in[5];
    const int*   dst    = (const int*)d_in[6];
    const int*   etype  = (const int*)d_in[7];

    float* out_attn = (float*)d_out;              // [E, 1, HEADS]
    float* out_ret  = out_attn + (size_t)EE * HEADS; // [N, FOUT]

    // workspace layout (bytes)
    char* ws = (char*)d_ws;
    float*    nf   = (float*)(ws);                              // 51.2 MB  [A..E]
    float*    a1   = (float*)(ws + 51200000);                   // 1.6 MB   [A..B]
    unsigned* M    = (unsigned*)(ws + 52800000);                // 1.6 MB   [B..C]
    float*    den  = (float*)(ws + 54400000);                   // 1.6 MB   [C..D]
    float*    hout = (float*)(ws + 56000000);                   // 51.2 MB  [post-D..F]
    float*    nt   = (float*)(ws + 56000000);                   // 25.6 MB  [A..B] (overlaps hout)

    // zero segment-max (mapped-uint 0 == -inf-ish floor) and denominator
    hipMemsetAsync(M,   0, (size_t)NN * HEADS * 4, stream);
    hipMemsetAsync(den, 0, (size_t)NN * HEADS * 4, stream);

    k_project<<<(NN + NPB - 1) / NPB, 256, 0, stream>>>(x, fc_w, attn_l, attn_r, nf, a1, nt);

    int eblk = (EE * HEADS + 255) / 256;
    k_logits<<<eblk, 256, 0, stream>>>(a1, nt, src, dst, etype, out_attn, M);
    k_expsum<<<eblk, 256, 0, stream>>>(dst, M, out_attn, den);
    k_norm  <<<eblk, 256, 0, stream>>>(dst, den, out_attn);

    // hout reuses nt's space: zero only after nt's last reader (k_logits) is queued
    hipMemsetAsync(hout, 0, (size_t)NN * HF * 4, stream);
    k_agg<<<EE, 256, 0, stream>>>(nf, out_attn, src, dst, hout);

    k_final<<<(NN * FOUT + 255) / 256, 256, 0, stream>>>(hout, bias, out_ret);
}

// Round 2
// 518.901 us; speedup vs baseline: 1.6826x; 1.6826x over previous
//
#include <hip/hip_runtime.h>
#include <math.h>

#define NN 50000
#define EE 800000
#define FIN 128
#define FOUT 32
#define HEADS 8
#define NT 16
#define HF 256          // HEADS*FOUT
#define TH (NT*HEADS)   // 128

// ---- float<->ordered-uint mapping for atomicMax on floats ----
__device__ __forceinline__ unsigned fmap(float f) {
    unsigned u = __float_as_uint(f);
    return (u & 0x80000000u) ? ~u : (u | 0x80000000u);
}
__device__ __forceinline__ float funmap(unsigned u) {
    u = (u & 0x80000000u) ? (u & 0x7FFFFFFFu) : ~u;
    return __uint_as_float(u);
}

// ---- Kernel A: projection + a1 + node_type, NPB nodes per 256-thread block ----
#define NPB 8
__global__ __launch_bounds__(256) void k_project(
    const float* __restrict__ x, const float* __restrict__ fc_w,
    const float* __restrict__ attn_l, const float* __restrict__ attn_r,
    float* __restrict__ nf, float* __restrict__ a1, float* __restrict__ nt)
{
    __shared__ float xs[NPB][FIN];
    __shared__ float ps[NPB][HF];
    const int t = threadIdx.x;
    const int node0 = blockIdx.x * NPB;

    for (int i = t; i < NPB * FIN; i += 256) {
        int ni = i >> 7, k = i & 127;
        int n = node0 + ni;
        xs[ni][k] = (n < NN) ? x[n * FIN + k] : 0.f;
    }
    __syncthreads();

    float acc[NPB];
#pragma unroll
    for (int i = 0; i < NPB; i++) acc[i] = 0.f;
    for (int k = 0; k < FIN; k++) {
        float w = fc_w[k * HF + t];
#pragma unroll
        for (int i = 0; i < NPB; i++) acc[i] += xs[i][k] * w;
    }
#pragma unroll
    for (int i = 0; i < NPB; i++) {
        ps[i][t] = acc[i];
        int n = node0 + i;
        if (n < NN) nf[n * HF + t] = acc[i];
    }
    __syncthreads();

    // a1: NPB*HEADS = 64 tasks
    if (t < NPB * HEADS) {
        int ni = t >> 3, h = t & 7;
        float s = 0.f;
#pragma unroll
        for (int f = 0; f < FOUT; f++) s += ps[ni][f * HEADS + h] * attn_l[f * HEADS + h];
        int n = node0 + ni;
        if (n < NN) a1[n * HEADS + h] = s;
    }
    // node_type: NPB*NT*HEADS = 1024 tasks
    for (int task = t; task < NPB * TH; task += 256) {
        int ni = task / TH;
        int rem = task % TH;
        int tt = rem >> 3, h = rem & 7;
        const float* ar = attn_r + tt * (FOUT * HEADS);
        float s = 0.f;
#pragma unroll
        for (int f = 0; f < FOUT; f++) s += ps[ni][f * HEADS + h] * ar[f * HEADS + h];
        int n = node0 + ni;
        if (n < NN) nt[n * TH + rem] = s;
    }
}

// ---- CSR build: histogram of dst ----
__global__ __launch_bounds__(256) void k_hist(
    const int* __restrict__ dst, int* __restrict__ deg)
{
    int e = blockIdx.x * 256 + threadIdx.x;
    if (e >= EE) return;
    atomicAdd(&deg[dst[e]], 1);
}

// ---- CSR build: single-block exclusive scan over deg -> rowptr ----
#define SCAN_T 1024
__global__ __launch_bounds__(1024) void k_scan(
    const int* __restrict__ deg, int* __restrict__ rowptr)
{
    __shared__ int part[SCAN_T];
    const int t = threadIdx.x;
    const int CH = (NN + SCAN_T - 1) / SCAN_T;  // 49
    int begin = t * CH;
    int end = begin + CH; if (end > NN) end = NN;
    if (begin > NN) begin = NN;
    int s = 0;
    for (int i = begin; i < end; i++) s += deg[i];
    part[t] = s;
    __syncthreads();
    // Hillis-Steele inclusive scan
    for (int off = 1; off < SCAN_T; off <<= 1) {
        int v = (t >= off) ? part[t - off] : 0;
        __syncthreads();
        part[t] += v;
        __syncthreads();
    }
    int excl = (t == 0) ? 0 : part[t - 1];
    for (int i = begin; i < end; i++) {
        rowptr[i] = excl;
        excl += deg[i];
    }
}

// ---- CSR build: scatter edge ids ----
__global__ __launch_bounds__(256) void k_scatter(
    const int* __restrict__ dst, const int* __restrict__ rowptr,
    int* __restrict__ cursor, int* __restrict__ eidx)
{
    int e = blockIdx.x * 256 + threadIdx.x;
    if (e >= EE) return;
    int d = dst[e];
    int pos = atomicAdd(&cursor[d], 1);
    eidx[rowptr[d] + pos] = e;
}

// ---- Kernel B: edge logits + leaky relu + atomic segment max ----
__global__ __launch_bounds__(256) void k_logits(
    const float* __restrict__ a1, const float* __restrict__ nt,
    const int* __restrict__ src, const int* __restrict__ dst,
    const int* __restrict__ et,
    float* __restrict__ A, unsigned* __restrict__ M)
{
    int idx = blockIdx.x * 256 + threadIdx.x;
    if (idx >= EE * HEADS) return;
    int e = idx >> 3, h = idx & 7;
    int d = dst[e], s = src[e], ty = et[e];
    float a = a1[d * HEADS + h] + nt[s * TH + ty * HEADS + h];
    a = (a > 0.f) ? a : 0.2f * a;
    A[idx] = a;
    atomicMax(&M[d * HEADS + h], fmap(a));
}

// ---- Kernel C: ex = exp(a - m[dst]); atomic segment sum ----
__global__ __launch_bounds__(256) void k_expsum(
    const int* __restrict__ dst, const unsigned* __restrict__ M,
    float* __restrict__ A, float* __restrict__ den)
{
    int idx = blockIdx.x * 256 + threadIdx.x;
    if (idx >= EE * HEADS) return;
    int e = idx >> 3, h = idx & 7;
    int d = dst[e];
    float m = funmap(M[d * HEADS + h]);
    float ex = expf(A[idx] - m);
    A[idx] = ex;
    atomicAdd(&den[d * HEADS + h], ex);
}

// ---- Fused: attn normalize (write-back) + gather-aggregate + bias/mean/ELU ----
// One 64-lane wave per dst node; lane owns columns j = lane*4 .. lane*4+3.
__global__ __launch_bounds__(256) void k_aggfused(
    const float* __restrict__ nf, const int* __restrict__ src,
    const int* __restrict__ rowptr, const int* __restrict__ deg,
    const int* __restrict__ eidx, const float* __restrict__ den,
    const float* __restrict__ bias, float* __restrict__ A,
    float* __restrict__ ret)
{
    const int wave = threadIdx.x >> 6;
    const int lane = threadIdx.x & 63;
    const int n = blockIdx.x * 4 + wave;
    if (n >= NN) return;
    const int start = rowptr[n];
    const int cnt = deg[n];
    const int half = lane & 1;  // columns j=lane*4+c have h=(lane*4+c)&7 = half*4+c

    float4 invden;
    {
        float4 dn = *(const float4*)(&den[n * HEADS + half * 4]);
        invden = make_float4(1.f / dn.x, 1.f / dn.y, 1.f / dn.z, 1.f / dn.w);
    }
    float4 acc = make_float4(0.f, 0.f, 0.f, 0.f);

    for (int i = 0; i < cnt; i++) {
        int e = eidx[start + i];
        int s = src[e];
        float4 ex = *(const float4*)(&A[e * HEADS + half * 4]);
        float4 at = make_float4(ex.x * invden.x, ex.y * invden.y,
                                ex.z * invden.z, ex.w * invden.w);
        if (lane < 2) *(float4*)(&A[e * HEADS + lane * 4]) = at;  // final attn, once per edge
        float4 v = *(const float4*)(&nf[(size_t)s * HF + lane * 4]);
        acc.x += v.x * at.x; acc.y += v.y * at.y;
        acc.z += v.z * at.z; acc.w += v.w * at.w;
    }

    // + bias (summed over the coset below = sum_h2 bias[h2*32+f2])
    float4 b = *(const float4*)(&bias[lane * 4]);
    acc.x += b.x; acc.y += b.y; acc.z += b.z; acc.w += b.w;

    // reduce over lanes differing in bits 3..5 (coset l&7): sums h2=0..7
    for (int m = 8; m <= 32; m <<= 1) {
        acc.x += __shfl_xor(acc.x, m, 64);
        acc.y += __shfl_xor(acc.y, m, 64);
        acc.z += __shfl_xor(acc.z, m, 64);
        acc.w += __shfl_xor(acc.w, m, 64);
    }
    if (lane < 8) {
        float4 o;
        o.x = acc.x * 0.125f; o.y = acc.y * 0.125f;
        o.z = acc.z * 0.125f; o.w = acc.w * 0.125f;
        o.x = (o.x > 0.f) ? o.x : (expf(o.x) - 1.f);
        o.y = (o.y > 0.f) ? o.y : (expf(o.y) - 1.f);
        o.z = (o.z > 0.f) ? o.z : (expf(o.z) - 1.f);
        o.w = (o.w > 0.f) ? o.w : (expf(o.w) - 1.f);
        *(float4*)(&ret[n * FOUT + lane * 4]) = o;
    }
}

extern "C" void kernel_launch(void* const* d_in, const int* in_sizes, int n_in,
                              void* d_out, int out_size, void* d_ws, size_t ws_size,
                              hipStream_t stream)
{
    const float* x      = (const float*)d_in[0];
    const float* fc_w   = (const float*)d_in[1];
    const float* attn_l = (const float*)d_in[2];
    const float* attn_r = (const float*)d_in[3];
    const float* bias   = (const float*)d_in[4];
    const int*   src    = (const int*)d_in[5];
    const int*   dst    = (const int*)d_in[6];
    const int*   etype  = (const int*)d_in[7];

    float* out_attn = (float*)d_out;                 // [E, 1, HEADS]
    float* out_ret  = out_attn + (size_t)EE * HEADS; // [N, FOUT]

    // workspace layout (bytes)
    char* ws = (char*)d_ws;
    float*    nf     = (float*)(ws);                    // 51.2 MB
    float*    a1     = (float*)(ws + 51200000);         // 1.6 MB
    unsigned* M      = (unsigned*)(ws + 52800000);      // 1.6 MB
    float*    den    = (float*)(ws + 54400000);         // 1.6 MB
    float*    nt     = (float*)(ws + 56000000);         // 25.6 MB
    int*      deg    = (int*)(ws + 81600000);           // 200 KB
    int*      cursor = (int*)(ws + 81800000);           // 200 KB
    int*      rowptr = (int*)(ws + 82000000);           // 200 KB
    int*      eidx   = (int*)(ws + 82200192);           // 3.2 MB

    // zero per-launch state: segment max, denom, deg+cursor (contiguous)
    hipMemsetAsync(M,   0, (size_t)NN * HEADS * 4, stream);
    hipMemsetAsync(den, 0, (size_t)NN * HEADS * 4, stream);
    hipMemsetAsync(deg, 0, (size_t)400000, stream);

    k_project<<<(NN + NPB - 1) / NPB, 256, 0, stream>>>(x, fc_w, attn_l, attn_r, nf, a1, nt);

    k_hist<<<(EE + 255) / 256, 256, 0, stream>>>(dst, deg);
    k_scan<<<1, SCAN_T, 0, stream>>>(deg, rowptr);
    k_scatter<<<(EE + 255) / 256, 256, 0, stream>>>(dst, rowptr, cursor, eidx);

    int eblk = (EE * HEADS + 255) / 256;
    k_logits<<<eblk, 256, 0, stream>>>(a1, nt, src, dst, etype, out_attn, M);
    k_expsum<<<eblk, 256, 0, stream>>>(dst, M, out_attn, den);

    k_aggfused<<<(NN + 3) / 4, 256, 0, stream>>>(nf, src, rowptr, deg, eidx, den,
                                                 bias, out_attn, out_ret);
}